// Round 3
// baseline (1715.071 us; speedup 1.0000x reference)
//
#include <hip/hip_runtime.h>
#include <hip/hip_bf16.h>

// Problem constants
#define H_ 128
#define W_ 128
#define HW 16384          // H*W
#define CIN 64
#define COUT 128
#define KK9 9
#define BATCH 8
#define NPIX (BATCH * HW) // 131072
#define KDIM 576          // CIN*KK9
#define VSTRIDE 580       // 576 + 4 pad

__device__ __forceinline__ float us2f(unsigned short u) {
    unsigned int v = ((unsigned int)u) << 16;
    float f;
    __builtin_memcpy(&f, &v, 4);
    return f;
}

template <bool F32>
__device__ __forceinline__ float ld_in(const void* p, long i) {
    if (F32) return ((const float*)p)[i];
    return us2f(((const unsigned short*)p)[i]);
}

// ---------------------------------------------------------------------------
// detect_dtype: decide whether inputs are stored f32 (flag=1) or bf16 (flag=0).
// f32 data read as bf16 pairs: low words have uniform-random exponent bits ->
// ~25% land at exp >= 0xC0 (|v| >= 2^65). True bf16 N(0,1) never does.
// ---------------------------------------------------------------------------
__global__ void detect_dtype(const unsigned short* __restrict__ xr,
                             float* __restrict__ flag) {
    int big = 0;
    for (int i = 0; i < 512; ++i) {
        int ex = (xr[i] >> 7) & 0xFF;
        big += (ex >= 0xC0);
    }
    flag[0] = big ? 1.0f : 0.0f;
}

// ---------------------------------------------------------------------------
// prep_weights: convert all weights/biases to f32 working layouts.
// wcat[27][64][9] = concat(offset_w, mask_w) flat (co-major).
// bias[32]: 0..17 offset_b, 18..26 mask_b.
// wT2[k][co], k = kk*64+ci, from conv_w[co][ci][kk].
// ---------------------------------------------------------------------------
template <bool F32>
__global__ void prep_weights(const void* __restrict__ offw,
                             const void* __restrict__ offb,
                             const void* __restrict__ maskw,
                             const void* __restrict__ maskb,
                             const void* __restrict__ convw,
                             const float* __restrict__ flag,
                             float* __restrict__ wcat,
                             float* __restrict__ bias,
                             float* __restrict__ wT2) {
    if ((flag[0] != 0.0f) != F32) return;
    int i = blockIdx.x * 256 + threadIdx.x;
    if (i < 15552) {
        wcat[i] = (i < 10368) ? ld_in<F32>(offw, i) : ld_in<F32>(maskw, i - 10368);
    } else if (i < 15584) {
        int j = i - 15552;
        float v = 0.0f;
        if (j < 18) v = ld_in<F32>(offb, j);
        else if (j < 27) v = ld_in<F32>(maskb, j - 18);
        bias[j] = v;
    } else if (i < 15584 + 73728) {
        int idx2 = i - 15584;
        int k  = idx2 >> 7;      // 0..575
        int co = idx2 & 127;
        int kk = k >> 6;         // 0..8
        int ci = k & 63;
        wT2[idx2] = ld_in<F32>(convw, co * 576 + ci * 9 + kk);
    }
}

// ---------------------------------------------------------------------------
// transpose_x: raw x NCHW (f32 or bf16 per flag) -> NHWC f32.
// Block: 64 channels x 64 pixels. Grid = 8 batches * 256 tiles.
// ---------------------------------------------------------------------------
template <bool F32>
__global__ __launch_bounds__(256) void transpose_x(const void* __restrict__ x,
                                                   const float* __restrict__ flag,
                                                   float* __restrict__ xn) {
    if ((flag[0] != 0.0f) != F32) return;
    __shared__ float tile[CIN][64 + 1];
    int blk  = blockIdx.x;
    int b    = blk >> 8;
    int pix0 = (blk & 255) * 64;
    int t    = threadIdx.x;
    int lane = t & 63;
    int grp  = t >> 6;
#pragma unroll
    for (int r = 0; r < 16; ++r) {
        int ci = r * 4 + grp;
        tile[ci][lane] = ld_in<F32>(x, (long)(b * CIN + ci) * HW + pix0 + lane);
    }
    __syncthreads();
#pragma unroll
    for (int r = 0; r < 16; ++r) {
        int px = r * 4 + grp;
        xn[(size_t)(b * HW + pix0 + px) * CIN + lane] = tile[lane][px];
    }
}

// ---------------------------------------------------------------------------
// conv_offmask: 3x3 conv from NHWC xn -> 18 offset channels (raw) + 9 mask
// channels (sigmoid). 1 pixel per thread; weight reads are thread-uniform.
// ---------------------------------------------------------------------------
__global__ __launch_bounds__(256) void conv_offmask(const float* __restrict__ xn,
                                                    const float* __restrict__ wcat,
                                                    const float* __restrict__ bias,
                                                    float* __restrict__ off_ws,
                                                    float* __restrict__ mask_ws) {
    int pix = blockIdx.x * 256 + threadIdx.x;
    int b   = pix >> 14;
    int rem = pix & 16383;
    int y   = rem >> 7;
    int xx  = rem & 127;

    float acc[27];
#pragma unroll
    for (int co = 0; co < 27; ++co) acc[co] = bias[co];

    const float* xb = xn + (size_t)b * HW * CIN;
#pragma unroll 1
    for (int tap = 0; tap < 9; ++tap) {
        int yy = y + tap / 3 - 1;
        int xq = xx + tap % 3 - 1;
        if (yy < 0 || yy >= H_ || xq < 0 || xq >= W_) continue;
        const float* base = xb + (size_t)(yy * W_ + xq) * CIN;
#pragma unroll 1
        for (int cq = 0; cq < 16; ++cq) {
            float4 xv = *(const float4*)(base + cq * 4);
            const float* wt = wcat + cq * 36 + tap;   // + co*KDIM + {0,9,18,27}
#pragma unroll
            for (int co = 0; co < 27; ++co) {
                const float* w = wt + co * KDIM;
                acc[co] = fmaf(xv.x, w[0],  acc[co]);
                acc[co] = fmaf(xv.y, w[9],  acc[co]);
                acc[co] = fmaf(xv.z, w[18], acc[co]);
                acc[co] = fmaf(xv.w, w[27], acc[co]);
            }
        }
    }
#pragma unroll
    for (int co = 0; co < 18; ++co)
        off_ws[(size_t)(b * 18 + co) * HW + rem] = acc[co];
#pragma unroll
    for (int co = 0; co < 9; ++co) {
        float z = acc[18 + co];
        mask_ws[(size_t)(b * 9 + co) * HW + rem] = 1.0f / (1.0f + __expf(-z));
    }
}

// ---------------------------------------------------------------------------
// deform_gemm: per block = 16 consecutive pixels.
// Phase 1: modulated bilinear-sampled v[16][576] into LDS (k = kk*64+ci).
// Phase 2: out[p][co] = sum_k v[p][k] * wT2[k][co]; 8 co per thread.
// Accumulates per-channel sum/sumsq for BN. Output f32 NCHW (pre-BN).
// ---------------------------------------------------------------------------
__global__ __launch_bounds__(256) void deform_gemm(const float* __restrict__ xn,
                                                   const float* __restrict__ off_ws,
                                                   const float* __restrict__ mask_ws,
                                                   const float* __restrict__ wT2,
                                                   float* __restrict__ out,
                                                   float* __restrict__ gstat) {
    __shared__ float vlds[16 * VSTRIDE];
    __shared__ float red[256];

    int t    = threadIdx.x;
    int pix0 = blockIdx.x * 16;
    int b    = pix0 >> 14;
    int rem0 = pix0 & 16383;
    int y    = rem0 >> 7;
    int x0   = rem0 & 127;

    // ---- phase 1: sampling ----
    {
        int p   = t >> 4;      // pixel 0..15
        int cig = t & 15;      // ci group 0..15
        int ci0 = cig * 4;
        int xx  = x0 + p;
        const float* offp  = off_ws + (size_t)b * 18 * HW + y * W_ + xx;
        const float* maskp = mask_ws + (size_t)b * 9 * HW + y * W_ + xx;
        const float* xnb   = xn + (size_t)b * HW * CIN;
#pragma unroll 1
        for (int kk = 0; kk < KK9; ++kk) {
            float offy = offp[(2 * kk) * HW];
            float offx = offp[(2 * kk + 1) * HW];
            float m    = maskp[kk * HW];
            float py = (float)(y + kk / 3 - 1) + offy;
            float px = (float)(xx + kk % 3 - 1) + offx;
            float y0f = floorf(py), x0f = floorf(px);
            int yi = (int)y0f, xi = (int)x0f;
            float wy1 = py - y0f, wx1 = px - x0f;
            float wy0 = 1.0f - wy1, wx0 = 1.0f - wx1;
            float v0 = 0.f, v1 = 0.f, v2 = 0.f, v3 = 0.f;
#pragma unroll
            for (int c = 0; c < 4; ++c) {
                int ys = yi + (c >> 1);
                int xs = xi + (c & 1);
                float wgt = ((c >> 1) ? wy1 : wy0) * ((c & 1) ? wx1 : wx0);
                bool ok = (ys >= 0) && (ys < H_) && (xs >= 0) && (xs < W_);
                if (ok) {
                    const float4 xv = *(const float4*)(xnb + (size_t)(ys * W_ + xs) * CIN + ci0);
                    v0 = fmaf(wgt, xv.x, v0);
                    v1 = fmaf(wgt, xv.y, v1);
                    v2 = fmaf(wgt, xv.z, v2);
                    v3 = fmaf(wgt, xv.w, v3);
                }
            }
            float4 v = make_float4(v0 * m, v1 * m, v2 * m, v3 * m);
            *(float4*)(vlds + p * VSTRIDE + kk * 64 + ci0) = v;
        }
    }
    __syncthreads();

    // ---- phase 2: dot with weights ----
    int cog = t & 15;
    int p2  = t >> 4;
    int co0 = cog * 8;
    float acc[8] = {0.f, 0.f, 0.f, 0.f, 0.f, 0.f, 0.f, 0.f};
    const float* vrow = vlds + p2 * VSTRIDE;
    const float* wp   = wT2 + co0;
#pragma unroll 2
    for (int k = 0; k < KDIM; k += 4) {
        float4 v4 = *(const float4*)(vrow + k);
        float vv[4] = {v4.x, v4.y, v4.z, v4.w};
#pragma unroll
        for (int i = 0; i < 4; ++i) {
            const float4 w0 = *(const float4*)(wp + (k + i) * COUT);
            const float4 w1 = *(const float4*)(wp + (k + i) * COUT + 4);
            float vi = vv[i];
            acc[0] = fmaf(vi, w0.x, acc[0]);
            acc[1] = fmaf(vi, w0.y, acc[1]);
            acc[2] = fmaf(vi, w0.z, acc[2]);
            acc[3] = fmaf(vi, w0.w, acc[3]);
            acc[4] = fmaf(vi, w1.x, acc[4]);
            acc[5] = fmaf(vi, w1.y, acc[5]);
            acc[6] = fmaf(vi, w1.z, acc[6]);
            acc[7] = fmaf(vi, w1.w, acc[7]);
        }
    }

    // raw output (pre-BN), f32 NCHW
    int remp = rem0 + p2;
    float* ob = out + (size_t)b * COUT * HW + remp;
#pragma unroll
    for (int j = 0; j < 8; ++j)
        ob[(size_t)(co0 + j) * HW] = acc[j];

    // ---- BN stats ----
    red[t] = 0.0f;
    __syncthreads();
#pragma unroll
    for (int j = 0; j < 8; ++j) {
        atomicAdd(&red[co0 + j], acc[j]);
        atomicAdd(&red[128 + co0 + j], acc[j] * acc[j]);
    }
    __syncthreads();
    atomicAdd(&gstat[(blockIdx.x & 15) * 256 + t], red[t]);
}

// ---------------------------------------------------------------------------
// bn_stats: fold 16 partial stat copies into mean / rstd. NaN/Inf guarded so
// corrupt stats can never silently zero the whole output.
// ---------------------------------------------------------------------------
__global__ void bn_stats(const float* __restrict__ gstat, float* __restrict__ mv) {
    int co = threadIdx.x;  // 128 threads
    float s = 0.f, ss = 0.f;
#pragma unroll
    for (int part = 0; part < 16; ++part) {
        s  += gstat[part * 256 + co];
        ss += gstat[part * 256 + 128 + co];
    }
    const float invN = 1.0f / (float)NPIX;
    float mean = s * invN;
    float var  = ss * invN - mean * mean;
    if (!isfinite(mean)) mean = 0.0f;
    float r = rsqrtf(fmaxf(var, 0.0f) + 1e-5f);
    if (!isfinite(r)) r = 1.0f;
    mv[co]       = mean;
    mv[128 + co] = r;
}

// ---------------------------------------------------------------------------
// bn_apply: in-place normalize + ReLU on d_out (f32 NCHW). float4 per thread.
// ---------------------------------------------------------------------------
__global__ __launch_bounds__(256) void bn_apply(float* __restrict__ out,
                                                const float* __restrict__ mv) {
    int gid = blockIdx.x * 256 + threadIdx.x;
    size_t i4 = (size_t)gid * 4;
    int co = ((int)(i4 >> 14)) & 127;   // 4 consecutive elems share a channel
    float mean = mv[co], rstd = mv[128 + co];
    float4* p = (float4*)(out + i4);
    float4 v = *p;
    v.x = fmaxf((v.x - mean) * rstd, 0.0f);
    v.y = fmaxf((v.y - mean) * rstd, 0.0f);
    v.z = fmaxf((v.z - mean) * rstd, 0.0f);
    v.w = fmaxf((v.w - mean) * rstd, 0.0f);
    *p = v;
}

// ---------------------------------------------------------------------------
extern "C" void kernel_launch(void* const* d_in, const int* in_sizes, int n_in,
                              void* d_out, int out_size, void* d_ws, size_t ws_size,
                              hipStream_t stream) {
    (void)in_sizes; (void)n_in; (void)out_size; (void)ws_size;
    const void* x     = d_in[0];
    const void* offw  = d_in[1];
    const void* offb  = d_in[2];
    const void* maskw = d_in[3];
    const void* maskb = d_in[4];
    const void* convw = d_in[5];

    float* ws      = (float*)d_ws;
    float* xn      = ws;                       // 8,388,608 f32 (NHWC x)
    float* off_ws  = xn + 8388608;             // 2,359,296 f32
    float* mask_ws = off_ws + 2359296;         // 1,179,648 f32
    float* wT2     = mask_ws + 1179648;        //    73,728 f32
    float* wcat    = wT2 + 73728;              //    15,552 f32
    float* bias    = wcat + 15552;             //        32 f32
    float* gstat   = bias + 32;                //     4,096 f32
    float* mv      = gstat + 4096;             //       256 f32
    float* flag    = mv + 256;                 //        16 f32
    float* out     = (float*)d_out;

    hipMemsetAsync(gstat, 0, 4096 * sizeof(float), stream);
    detect_dtype<<<1, 1, 0, stream>>>((const unsigned short*)x, flag);
    prep_weights<true><<<349, 256, 0, stream>>>(offw, offb, maskw, maskb, convw, flag, wcat, bias, wT2);
    prep_weights<false><<<349, 256, 0, stream>>>(offw, offb, maskw, maskb, convw, flag, wcat, bias, wT2);
    transpose_x<true><<<2048, 256, 0, stream>>>(x, flag, xn);
    transpose_x<false><<<2048, 256, 0, stream>>>(x, flag, xn);
    conv_offmask<<<512, 256, 0, stream>>>(xn, wcat, bias, off_ws, mask_ws);
    deform_gemm<<<8192, 256, 0, stream>>>(xn, off_ws, mask_ws, wT2, out, gstat);
    bn_stats<<<1, 128, 0, stream>>>(gstat, mv);
    bn_apply<<<16384, 256, 0, stream>>>(out, mv);
}

// Round 4
// 314.823 us; speedup vs baseline: 5.4477x; 5.4477x over previous
//
#include <hip/hip_runtime.h>
#include <hip/hip_bf16.h>

// Problem constants
#define H_ 128
#define W_ 128
#define HW 16384          // H*W
#define CIN 64
#define COUT 128
#define KK9 9
#define BATCH 8
#define NPIX (BATCH * HW) // 131072
#define KDIM 576          // CIN*KK9
#define ROWB 72           // LDS row pitch in bf16 elems (64 + 8 pad -> 2-way max)

typedef short bf16x8 __attribute__((ext_vector_type(8)));
typedef float f32x4  __attribute__((ext_vector_type(4)));
typedef unsigned short ushort_t;

__device__ __forceinline__ float us2f(unsigned short u) {
    unsigned int v = ((unsigned int)u) << 16;
    float f;
    __builtin_memcpy(&f, &v, 4);
    return f;
}
__device__ __forceinline__ unsigned short f2us_bf(float f) {
    __hip_bfloat16 h = __float2bfloat16(f);
    unsigned short u;
    __builtin_memcpy(&u, &h, 2);
    return u;
}
__device__ __forceinline__ unsigned int pack2(float a, float b) {
    return (unsigned int)f2us_bf(a) | ((unsigned int)f2us_bf(b) << 16);
}

template <bool F32>
__device__ __forceinline__ float ld_in(const void* p, long i) {
    if (F32) return ((const float*)p)[i];
    return us2f(((const unsigned short*)p)[i]);
}

// ---------------------------------------------------------------------------
// detect_dtype: inputs f32 (flag=1) vs bf16 (flag=0). f32 read as bf16 pairs
// has ~25% of low words with exponent >= 0xC0; true bf16 N(0,1) never.
// ---------------------------------------------------------------------------
__global__ void detect_dtype(const unsigned short* __restrict__ xr,
                             float* __restrict__ flag) {
    int big = 0;
    for (int i = 0; i < 512; ++i) {
        int ex = (xr[i] >> 7) & 0xFF;
        big += (ex >= 0xC0);
    }
    flag[0] = big ? 1.0f : 0.0f;
}

// ---------------------------------------------------------------------------
// prep_weights: build bf16 MFMA weight layouts + f32 bias.
// wTb  [128 co][576 k] bf16, k = kk*64+ci, from conv_w[co][ci][kk]  (W^T)
// wcatb[32 co2][576 k] bf16 (27 real rows: 18 offset + 9 mask, rest 0)
// bias [32] f32 (0..17 offb, 18..26 maskb)
// ---------------------------------------------------------------------------
template <bool F32>
__global__ void prep_weights(const void* __restrict__ offw,
                             const void* __restrict__ offb,
                             const void* __restrict__ maskw,
                             const void* __restrict__ maskb,
                             const void* __restrict__ convw,
                             const float* __restrict__ flag,
                             ushort_t* __restrict__ wTb,
                             ushort_t* __restrict__ wcatb,
                             float* __restrict__ bias) {
    if ((flag[0] != 0.0f) != F32) return;
    int i = blockIdx.x * 256 + threadIdx.x;
    if (i < 73728) {
        int co = i / KDIM, k = i - co * KDIM;
        int kk = k >> 6, ci = k & 63;
        wTb[i] = f2us_bf(ld_in<F32>(convw, (long)co * KDIM + ci * 9 + kk));
    } else if (i < 73728 + 18432) {
        int j = i - 73728;
        int co2 = j / KDIM, k = j - co2 * KDIM;
        int kk = k >> 6, ci = k & 63;
        float v = 0.0f;
        if (co2 < 18)      v = ld_in<F32>(offw,  (long)co2 * KDIM + ci * 9 + kk);
        else if (co2 < 27) v = ld_in<F32>(maskw, (long)(co2 - 18) * KDIM + ci * 9 + kk);
        wcatb[j] = f2us_bf(v);
    } else if (i < 73728 + 18432 + 32) {
        int j = i - 73728 - 18432;
        float v = 0.0f;
        if (j < 18)      v = ld_in<F32>(offb, j);
        else if (j < 27) v = ld_in<F32>(maskb, j - 18);
        bias[j] = v;
    }
}

// ---------------------------------------------------------------------------
// transpose_x: raw x NCHW -> NHWC f32.
// ---------------------------------------------------------------------------
template <bool F32>
__global__ __launch_bounds__(256) void transpose_x(const void* __restrict__ x,
                                                   const float* __restrict__ flag,
                                                   float* __restrict__ xn) {
    if ((flag[0] != 0.0f) != F32) return;
    __shared__ float tile[CIN][64 + 1];
    int blk  = blockIdx.x;
    int b    = blk >> 8;
    int pix0 = (blk & 255) * 64;
    int t    = threadIdx.x;
    int lane = t & 63;
    int grp  = t >> 6;
#pragma unroll
    for (int r = 0; r < 16; ++r) {
        int ci = r * 4 + grp;
        tile[ci][lane] = ld_in<F32>(x, (long)(b * CIN + ci) * HW + pix0 + lane);
    }
    __syncthreads();
#pragma unroll
    for (int r = 0; r < 16; ++r) {
        int px = r * 4 + grp;
        xn[(size_t)(b * HW + pix0 + px) * CIN + lane] = tile[lane][px];
    }
}

// ---------------------------------------------------------------------------
// conv_offmask_mfma: implicit-GEMM 3x3 conv -> 27 channels via MFMA.
// Block = 64 px x 32 co (2 n-tiles), 4 waves of 16 px. K = 576 in 9 tap-chunks.
// ---------------------------------------------------------------------------
__global__ __launch_bounds__(256) void conv_offmask_mfma(
        const float* __restrict__ xn,
        const ushort_t* __restrict__ wcatb,
        const float* __restrict__ bias,
        float* __restrict__ off_ws,
        float* __restrict__ mask_ws) {
    __shared__ ushort_t ldsA[64 * ROWB];
    __shared__ ushort_t ldsB[32 * ROWB];

    int t    = threadIdx.x;
    int pix0 = blockIdx.x * 64;
    int b    = pix0 >> 14;
    int rem0 = pix0 & 16383;
    int y    = rem0 >> 7;
    int x0   = rem0 & 127;

    // sampling mapping: 1 thread = 1 pixel x 16 channels
    int sp = t >> 2;
    int cq = t & 3;
    int xx = x0 + sp;
    const float* xnb = xn + (size_t)b * HW * CIN;

    // B staging mapping: 32 rows, 8 threads/row, 8 bf16 each
    int brow = t >> 3;
    int bprt = t & 7;

    // MFMA mapping
    int wave = t >> 6;
    int lane = t & 63;
    int mrow = lane & 15;
    int quad = lane >> 4;
    f32x4 acc[2];
    acc[0] = (f32x4){0.f, 0.f, 0.f, 0.f};
    acc[1] = (f32x4){0.f, 0.f, 0.f, 0.f};

    const ushort_t* arow = ldsA + (wave * 16 + mrow) * ROWB + quad * 8;
    const ushort_t* brow_p = ldsB + mrow * ROWB + quad * 8;

#pragma unroll 1
    for (int kk = 0; kk < KK9; ++kk) {
        // stage B chunk: wcatb[row][kk*64 .. +64]
        *(uint4*)(ldsB + brow * ROWB + bprt * 8) =
            *(const uint4*)(wcatb + brow * KDIM + kk * 64 + bprt * 8);

        // stage A chunk: shifted-window x
        {
            int yy = y + kk / 3 - 1;
            int xq = xx + kk % 3 - 1;
            unsigned int w[8];
            if (yy >= 0 && yy < H_ && xq >= 0 && xq < W_) {
                const float* src = xnb + (size_t)(yy * W_ + xq) * CIN + cq * 16;
#pragma unroll
                for (int q = 0; q < 4; ++q) {
                    float4 xv = *(const float4*)(src + q * 4);
                    w[q * 2]     = pack2(xv.x, xv.y);
                    w[q * 2 + 1] = pack2(xv.z, xv.w);
                }
            } else {
#pragma unroll
                for (int q = 0; q < 8; ++q) w[q] = 0u;
            }
            ushort_t* dst = ldsA + sp * ROWB + cq * 16;
            *(uint4*)dst       = make_uint4(w[0], w[1], w[2], w[3]);
            *(uint4*)(dst + 8) = make_uint4(w[4], w[5], w[6], w[7]);
        }
        __syncthreads();

#pragma unroll
        for (int ks = 0; ks < 2; ++ks) {
            bf16x8 af = *(const bf16x8*)(arow + ks * 32);
#pragma unroll
            for (int n = 0; n < 2; ++n) {
                bf16x8 bf = *(const bf16x8*)(brow_p + n * 16 * ROWB + ks * 32);
                acc[n] = __builtin_amdgcn_mfma_f32_16x16x32_bf16(af, bf, acc[n], 0, 0, 0);
            }
        }
        __syncthreads();
    }

    // epilogue: co2 = n*16 + mrow; px = wave*16 + quad*4 + r
#pragma unroll
    for (int n = 0; n < 2; ++n) {
        int co2 = n * 16 + mrow;
        if (co2 >= 27) continue;
        float bs = bias[co2];
#pragma unroll
        for (int r = 0; r < 4; ++r) {
            int px = wave * 16 + quad * 4 + r;
            float v = acc[n][r] + bs;
            if (co2 < 18) {
                off_ws[(size_t)(b * 18 + co2) * HW + rem0 + px] = v;
            } else {
                mask_ws[(size_t)(b * 9 + (co2 - 18)) * HW + rem0 + px] =
                    1.0f / (1.0f + __expf(-v));
            }
        }
    }
}

// ---------------------------------------------------------------------------
// deform_mfma: fused bilinear sampling + GEMM via MFMA.
// Block = 64 px x 128 co (8 n-tiles), 4 waves of 16 px. K = 576 in 9 tap-chunks.
// Per tap: sample V-chunk [64px][64ci] bf16 -> LDS A; stage W^T chunk -> LDS B;
// 2 k-steps x 8 MFMAs per wave. Output f32 NCHW pre-BN + BN stats.
// ---------------------------------------------------------------------------
__global__ __launch_bounds__(256) void deform_mfma(
        const float* __restrict__ xn,
        const float* __restrict__ off_ws,
        const float* __restrict__ mask_ws,
        const ushort_t* __restrict__ wTb,
        float* __restrict__ out,
        float* __restrict__ gstat) {
    __shared__ ushort_t ldsA[64 * ROWB];
    __shared__ ushort_t ldsB[128 * ROWB];
    __shared__ float red[256];

    int t    = threadIdx.x;
    int pix0 = blockIdx.x * 64;
    int b    = pix0 >> 14;
    int rem0 = pix0 & 16383;
    int y    = rem0 >> 7;
    int x0   = rem0 & 127;

    // sampling mapping
    int sp = t >> 2;
    int cq = t & 3;
    int xx = x0 + sp;
    const float* xnb   = xn + (size_t)b * HW * CIN;
    const float* offp  = off_ws  + (size_t)b * 18 * HW + y * W_ + xx;
    const float* maskp = mask_ws + (size_t)b * 9  * HW + y * W_ + xx;

    // B staging mapping: 128 rows, 2 threads/row, 32 bf16 each
    int bco = t >> 1;
    int bh  = t & 1;
    const ushort_t* wsrc = wTb + bco * KDIM + bh * 32;
    ushort_t* bdst = ldsB + bco * ROWB + bh * 32;

    // MFMA mapping
    int wave = t >> 6;
    int lane = t & 63;
    int mrow = lane & 15;
    int quad = lane >> 4;
    f32x4 acc[8];
#pragma unroll
    for (int n = 0; n < 8; ++n) acc[n] = (f32x4){0.f, 0.f, 0.f, 0.f};

    const ushort_t* arow = ldsA + (wave * 16 + mrow) * ROWB + quad * 8;
    const ushort_t* brow = ldsB + mrow * ROWB + quad * 8;

#pragma unroll 1
    for (int kk = 0; kk < KK9; ++kk) {
        // ---- stage B chunk (64 B per thread) ----
        {
            const ushort_t* s = wsrc + kk * 64;
            uint4 b0 = *(const uint4*)(s);
            uint4 b1 = *(const uint4*)(s + 8);
            uint4 b2 = *(const uint4*)(s + 16);
            uint4 b3 = *(const uint4*)(s + 24);
            *(uint4*)(bdst)      = b0;
            *(uint4*)(bdst + 8)  = b1;
            *(uint4*)(bdst + 16) = b2;
            *(uint4*)(bdst + 24) = b3;
        }

        // ---- sample V chunk: bilinear + mask, 16 channels ----
        {
            float offy = offp[(2 * kk) * HW];
            float offx = offp[(2 * kk + 1) * HW];
            float m    = maskp[kk * HW];
            float py = (float)(y + kk / 3 - 1) + offy;
            float px = (float)(xx + kk % 3 - 1) + offx;
            float y0f = floorf(py), x0f = floorf(px);
            int yi = (int)y0f, xi = (int)x0f;
            float wy1 = py - y0f, wx1 = px - x0f;
            float wy0 = 1.0f - wy1, wx0 = 1.0f - wx1;
            float v[16];
#pragma unroll
            for (int j = 0; j < 16; ++j) v[j] = 0.0f;
#pragma unroll
            for (int c = 0; c < 4; ++c) {
                int ys = yi + (c >> 1);
                int xs = xi + (c & 1);
                float wgt = ((c >> 1) ? wy1 : wy0) * ((c & 1) ? wx1 : wx0);
                if (ys >= 0 && ys < H_ && xs >= 0 && xs < W_) {
                    const float* src = xnb + (size_t)(ys * W_ + xs) * CIN + cq * 16;
#pragma unroll
                    for (int q = 0; q < 4; ++q) {
                        float4 xv = *(const float4*)(src + q * 4);
                        v[q * 4 + 0] = fmaf(wgt, xv.x, v[q * 4 + 0]);
                        v[q * 4 + 1] = fmaf(wgt, xv.y, v[q * 4 + 1]);
                        v[q * 4 + 2] = fmaf(wgt, xv.z, v[q * 4 + 2]);
                        v[q * 4 + 3] = fmaf(wgt, xv.w, v[q * 4 + 3]);
                    }
                }
            }
            unsigned int w[8];
#pragma unroll
            for (int j = 0; j < 8; ++j)
                w[j] = pack2(v[2 * j] * m, v[2 * j + 1] * m);
            ushort_t* dst = ldsA + sp * ROWB + cq * 16;
            *(uint4*)dst       = make_uint4(w[0], w[1], w[2], w[3]);
            *(uint4*)(dst + 8) = make_uint4(w[4], w[5], w[6], w[7]);
        }
        __syncthreads();

        // ---- MFMA: 2 k-steps x 8 n-tiles ----
#pragma unroll
        for (int ks = 0; ks < 2; ++ks) {
            bf16x8 af = *(const bf16x8*)(arow + ks * 32);
#pragma unroll
            for (int n = 0; n < 8; ++n) {
                bf16x8 bf = *(const bf16x8*)(brow + n * 16 * ROWB + ks * 32);
                acc[n] = __builtin_amdgcn_mfma_f32_16x16x32_bf16(af, bf, acc[n], 0, 0, 0);
            }
        }
        __syncthreads();
    }

    // ---- epilogue: store f32 NCHW + BN stats ----
    red[t] = 0.0f;
    __syncthreads();
    float* ob = out + (size_t)b * COUT * HW + rem0;
#pragma unroll
    for (int n = 0; n < 8; ++n) {
        int co = n * 16 + mrow;
        float s = 0.f, ss = 0.f;
#pragma unroll
        for (int r = 0; r < 4; ++r) {
            int px = wave * 16 + quad * 4 + r;
            float v = acc[n][r];
            ob[(size_t)co * HW + px] = v;
            s += v;
            ss += v * v;
        }
        atomicAdd(&red[co], s);
        atomicAdd(&red[128 + co], ss);
    }
    __syncthreads();
    atomicAdd(&gstat[(blockIdx.x & 15) * 256 + t], red[t]);
}

// ---------------------------------------------------------------------------
// bn_stats: fold 16 partial copies -> mean / rstd (NaN-guarded).
// ---------------------------------------------------------------------------
__global__ void bn_stats(const float* __restrict__ gstat, float* __restrict__ mv) {
    int co = threadIdx.x;  // 128 threads
    float s = 0.f, ss = 0.f;
#pragma unroll
    for (int part = 0; part < 16; ++part) {
        s  += gstat[part * 256 + co];
        ss += gstat[part * 256 + 128 + co];
    }
    const float invN = 1.0f / (float)NPIX;
    float mean = s * invN;
    float var  = ss * invN - mean * mean;
    if (!isfinite(mean)) mean = 0.0f;
    float r = rsqrtf(fmaxf(var, 0.0f) + 1e-5f);
    if (!isfinite(r)) r = 1.0f;
    mv[co]       = mean;
    mv[128 + co] = r;
}

// ---------------------------------------------------------------------------
// bn_apply: in-place normalize + ReLU on d_out (f32 NCHW), float4/thread.
// ---------------------------------------------------------------------------
__global__ __launch_bounds__(256) void bn_apply(float* __restrict__ out,
                                                const float* __restrict__ mv) {
    int gid = blockIdx.x * 256 + threadIdx.x;
    size_t i4 = (size_t)gid * 4;
    int co = ((int)(i4 >> 14)) & 127;
    float mean = mv[co], rstd = mv[128 + co];
    float4* p = (float4*)(out + i4);
    float4 v = *p;
    v.x = fmaxf((v.x - mean) * rstd, 0.0f);
    v.y = fmaxf((v.y - mean) * rstd, 0.0f);
    v.z = fmaxf((v.z - mean) * rstd, 0.0f);
    v.w = fmaxf((v.w - mean) * rstd, 0.0f);
    *p = v;
}

// ---------------------------------------------------------------------------
extern "C" void kernel_launch(void* const* d_in, const int* in_sizes, int n_in,
                              void* d_out, int out_size, void* d_ws, size_t ws_size,
                              hipStream_t stream) {
    (void)in_sizes; (void)n_in; (void)out_size; (void)ws_size;
    const void* x     = d_in[0];
    const void* offw  = d_in[1];
    const void* offb  = d_in[2];
    const void* maskw = d_in[3];
    const void* maskb = d_in[4];
    const void* convw = d_in[5];

    float* ws      = (float*)d_ws;
    float* xn      = ws;                       // 8,388,608 f32 (NHWC x)
    float* off_ws  = xn + 8388608;             // 2,359,296 f32
    float* mask_ws = off_ws + 2359296;         // 1,179,648 f32
    float* bias    = mask_ws + 1179648;        //        32 f32
    float* gstat   = bias + 32;                //     4,096 f32
    float* mv      = gstat + 4096;             //       256 f32
    float* flag    = mv + 256;                 //        16 f32
    ushort_t* wTb  = (ushort_t*)(flag + 16);   //    73,728 bf16
    ushort_t* wcatb = wTb + 73728;             //    18,432 bf16
    float* out     = (float*)d_out;

    hipMemsetAsync(gstat, 0, 4096 * sizeof(float), stream);
    detect_dtype<<<1, 1, 0, stream>>>((const unsigned short*)x, flag);
    prep_weights<true><<<361, 256, 0, stream>>>(offw, offb, maskw, maskb, convw, flag, wTb, wcatb, bias);
    prep_weights<false><<<361, 256, 0, stream>>>(offw, offb, maskw, maskb, convw, flag, wTb, wcatb, bias);
    transpose_x<true><<<2048, 256, 0, stream>>>(x, flag, xn);
    transpose_x<false><<<2048, 256, 0, stream>>>(x, flag, xn);
    conv_offmask_mfma<<<2048, 256, 0, stream>>>(xn, wcatb, bias, off_ws, mask_ws);
    deform_mfma<<<2048, 256, 0, stream>>>(xn, off_ws, mask_ws, wTb, out, gstat);
    bn_stats<<<1, 128, 0, stream>>>(gstat, mv);
    bn_apply<<<16384, 256, 0, stream>>>(out, mv);
}